// Round 6
// baseline (8265.253 us; speedup 1.0000x reference)
//
#include <hip/hip_runtime.h>
#include <cstdint>

// ---------------------------------------------------------------------------
// BiLSTM-CRF on MI355X.
// Sizes: V=100000 E=300 H=256 S=4096 L=32 NC=64 CE=25 CO=25 T=12 START=10 STOP=11
// Output: f32[1] = forward_score - gold_score
//
// k_lstm design (round 9, MFMA): 512 threads/block (8 waves, 2/SIMD), 1
// block/direction. Wave w owns W-rows [w*128, w*128+128) (row = gate*256+cell).
// Per step, per wave: 8 row-tiles x 8 k-tiles of mfma_f32_16x16x32_f16 with
// h REPLICATED across B's 16 columns (16-lane groups broadcast-read the same
// 16B of hbuf) -> every D column holds the gate pre-activations; lanes with
// (lane&15)==0 write D (4 consecutive rows each) to gates[] in LDS.
// A-frags: kt0..3 pinned to AGPRs ("+a" tie-asm, 128 regs), kt4..5 pinned to
// arch VGPRs (64), kt6..7 streamed from a 128 KiB LDS tier. D layout per m89:
// col=lane&15, row=(lane>>4)*4+reg. Epilogue: threads 0..255 (waves 0-3) read
// 4 gates + gi, update c/h, write f16 h pairs to double-buffered hbuf.
// Two barriers/step; hs global store delayed one step.
// ---------------------------------------------------------------------------

#define S_LEN 4096
#define EMB_LD 328            // embeds row stride (325 padded to 16B multiple)

typedef _Float16 half2_t __attribute__((ext_vector_type(2)));
typedef _Float16 f16x8_t __attribute__((ext_vector_type(8)));
typedef float    f32x4_t __attribute__((ext_vector_type(4)));
typedef unsigned int u32x4_t __attribute__((ext_vector_type(4)));

__device__ __forceinline__ unsigned int pack2f16(float a, float b) {
    union { _Float16 h[2]; unsigned int u; } v;
    v.h[0] = (_Float16)a; v.h[1] = (_Float16)b; return v.u;
}

__device__ __forceinline__ float sigm(float x) { return 1.0f / (1.0f + __expf(-x)); }

__device__ __forceinline__ float ftanh(float x) {
    float ax = fabsf(x);
    float e = __expf(-2.0f * ax);          // in (0,1], no overflow
    float t = (1.0f - e) / (1.0f + e);
    return copysignf(t, x);
}

// ---------------------------------------------------------------------------
// Workspace layout (bytes, all 256-aligned)
// ---------------------------------------------------------------------------
static constexpr size_t WS_EMBEDS = 0;                                // f32[4096][328]
static constexpr size_t WS_GI     = WS_EMBEDS + (size_t)4096*328*4;   // f32[2][4096][1024] ([dir][s][row])
static constexpr size_t WS_WPK    = WS_GI     + (size_t)2*4096*1024*4;// uint4[2][8][6][8][64] reg-tier A-frags
static constexpr size_t WS_WLT    = WS_WPK    + (size_t)2*8*6*8*64*16;// uint4[2][8][2][8][64] LDS-tier A-frags
static constexpr size_t WS_CFEAT  = WS_WLT    + (size_t)2*8*2*8*64*16;// f32[4096][25]
static constexpr size_t WS_HS     = WS_CFEAT  + (size_t)4096*25*4;    // f32[2][4096][256]
static constexpr size_t WS_FEATS  = WS_HS     + (size_t)2*4096*256*4; // f32[4096][12]
static constexpr size_t WS_CHUNKS = WS_FEATS  + (size_t)4096*12*4;    // f32[256][144]
static constexpr size_t WS_LVL2   = WS_CHUNKS + (size_t)256*144*4;    // f32[16][144]
static constexpr size_t WS_SCAL   = WS_LVL2   + (size_t)16*144*4;     // f32 scalars

// ---------------------------------------------------------------------------
// K1: pack Whh (fwd+bwd) into MFMA A-fragment order.
// Entry (dir,w,kt,rt,lane): 8 f16 = W[w*128+rt*16+(lane&15)][kt*32+(lane>>4)*8 + 0..7]
// kt 0..5 -> wpk (register tier), kt 6..7 -> wlt (LDS tier).
// ---------------------------------------------------------------------------
__global__ void k_pack(const float* __restrict__ whhf, const float* __restrict__ whhb,
                       uint4* __restrict__ wpk, uint4* __restrict__ wlt) {
    int idx = blockIdx.x * 256 + threadIdx.x;           // 0..65535
    int lane = idx & 63;
    int rt   = (idx >> 6) & 7;
    int kt   = (idx >> 9) & 7;
    int w    = (idx >> 12) & 7;
    int dir  = (idx >> 15) & 1;
    const float* W = (dir ? whhb : whhf);
    int row = w * 128 + rt * 16 + (lane & 15);
    int k0  = kt * 32 + (lane >> 4) * 8;
    const float* src = W + (size_t)row * 256 + k0;
    uint4 v;
    v.x = pack2f16(src[0], src[1]);
    v.y = pack2f16(src[2], src[3]);
    v.z = pack2f16(src[4], src[5]);
    v.w = pack2f16(src[6], src[7]);
    if (kt < 6) wpk[(size_t)(((dir*8 + w)*6 + kt)*8 + rt)*64 + lane] = v;
    else        wlt[(size_t)(((dir*8 + w)*2 + (kt-6))*8 + rt)*64 + lane] = v;
}

// ---------------------------------------------------------------------------
// K2: char CNN  (one block per word)
// ---------------------------------------------------------------------------
__global__ void k_charcnn(const int* __restrict__ chars, const float* __restrict__ cemb,
                          const float* __restrict__ convw, const float* __restrict__ convb,
                          float* __restrict__ cfeat) {
    int s = blockIdx.x, tid = threadIdx.x;              // 128 threads
    __shared__ float ce[32][25];
    __shared__ float wz[1875];                          // [25][3][25]
    __shared__ float bias[25];
    __shared__ float conv[850];                         // [34][25]
    for (int i = tid; i < 800; i += 128)
        ce[i / 25][i % 25] = cemb[chars[s * 32 + i / 25] * 25 + (i % 25)];
    for (int i = tid; i < 1875; i += 128) wz[i] = convw[i];
    if (tid < 25) bias[tid] = convb[tid];
    __syncthreads();
    for (int p = tid; p < 850; p += 128) {
        int tt = p / 25, o = p % 25;
        float acc = 0.f;
        #pragma unroll
        for (int kh = 0; kh < 3; kh++) {
            int tr = tt - 2 + kh;
            if (tr >= 0 && tr < 32) {
                const float* wrow = &wz[o * 75 + kh * 25];
                #pragma unroll
                for (int kw = 0; kw < 25; kw++) acc += ce[tr][kw] * wrow[kw];
            }
        }
        conv[p] = acc;
    }
    __syncthreads();
    if (tid < 25) {
        float m = conv[tid];
        for (int tt = 1; tt < 34; tt++) m = fmaxf(m, conv[tt * 25 + tid]);
        cfeat[s * 25 + tid] = m + bias[tid];
    }
}

// ---------------------------------------------------------------------------
// K3: embeds[s] = [ word_embed[sentence[s]] (300) | cfeat[s] (25) ]  stride 328
// ---------------------------------------------------------------------------
__global__ void k_embeds(const int* __restrict__ sentence, const float* __restrict__ wemb,
                         const float* __restrict__ cfeat, float* __restrict__ embeds) {
    int s = blockIdx.x, tid = threadIdx.x;              // 128 threads
    const float4* src = (const float4*)(wemb + (size_t)sentence[s] * 300);
    float4* dst = (float4*)(embeds + (size_t)s * EMB_LD);
    for (int i = tid; i < 75; i += 128) dst[i] = src[i];
    if (tid < 25) embeds[(size_t)s * EMB_LD + 300 + tid] = cfeat[s * 25 + tid];
    if (tid >= 25 && tid < 28) embeds[(size_t)s * EMB_LD + 325 + (tid - 25)] = 0.f; // pad
}

// ---------------------------------------------------------------------------
// K4: GEMM  gi = embeds @ Wih^T + b, output layout [dir][s][row] (row = g*256+c)
// ---------------------------------------------------------------------------
__global__ __launch_bounds__(256) void k_gemm(const float* __restrict__ A,
        const float* __restrict__ Bf, const float* __restrict__ Bb,
        const float* __restrict__ bf, const float* __restrict__ bb,
        float* __restrict__ gi) {
    int bs = blockIdx.x;            // s-tile  [0,64)
    int br = blockIdx.y;            // row-tile [0,32)
    int dir = br >> 4;
    int row0 = (br & 15) * 64;
    const float* B = dir ? Bb : Bf;
    const float* bias = dir ? bb : bf;
    __shared__ float As[16][65], Bs[16][65];
    int tid = threadIdx.x;
    int tx = tid & 15, ty = tid >> 4;
    int s0 = bs * 64;
    float acc[4][4] = {};
    int lr = tid >> 2, lc0 = (tid & 3) * 4;
    for (int k0 = 0; k0 < 325; k0 += 16) {
        #pragma unroll
        for (int i = 0; i < 4; i++) {
            int k = k0 + lc0 + i;
            As[lc0 + i][lr] = (k < 325) ? A[(size_t)(s0 + lr) * EMB_LD + k] : 0.f;
            Bs[lc0 + i][lr] = (k < 325) ? B[(size_t)(row0 + lr) * 325 + k] : 0.f;
        }
        __syncthreads();
        #pragma unroll
        for (int kk = 0; kk < 16; kk++) {
            float a[4], b[4];
            #pragma unroll
            for (int i = 0; i < 4; i++) a[i] = As[kk][ty * 4 + i];
            #pragma unroll
            for (int j = 0; j < 4; j++) b[j] = Bs[kk][tx * 4 + j];
            #pragma unroll
            for (int i = 0; i < 4; i++)
                #pragma unroll
                for (int j = 0; j < 4; j++) acc[i][j] += a[i] * b[j];
        }
        __syncthreads();
    }
    #pragma unroll
    for (int i = 0; i < 4; i++)
        #pragma unroll
        for (int j = 0; j < 4; j++) {
            int row = row0 + tx * 4 + j;                 // 0..1023 = gate*256+cell
            int s   = s0 + ty * 4 + i;
            gi[(size_t)dir * 4194304 + (size_t)s * 1024 + row] = acc[i][j] + bias[row];
        }
}

// ---------------------------------------------------------------------------
// K5: recurrence via MFMA. grid=2 (direction), 512 threads, 2 waves/SIMD.
// ---------------------------------------------------------------------------
#define LSTM_LDS_BYTES (131072 + 1024 + 4096)   // A-tier + hbuf + gates = 136192

__global__ __launch_bounds__(512, 2)
void k_lstm(const uint4* __restrict__ wpk, const uint4* __restrict__ wlt,
            const float* __restrict__ gi, float* __restrict__ hs) {
    const int dir  = blockIdx.x;
    const int tid  = threadIdx.x;                       // 0..511
    const int w    = tid >> 6;                          // wave = row-block
    const int lane = tid & 63;
    const int lr   = lane & 15;
    const int lg   = lane >> 4;

    extern __shared__ char smem[];
    uint4* wt          = (uint4*)smem;                  // [8w*2kt2*8rt][64] A-frags kt 6,7
    unsigned int* hbuf = (unsigned int*)(smem + 131072);// 2 buffers x 128 f16-pairs
    float* gates       = (float*)(smem + 132096);       // [1024] gate pre-activations

    // ---- register-tier A-frags: kt0..3 pinned AGPR, kt4..5 pinned arch ----
    u32x4_t aR[6][8];
    {
        const uint4* wb = wpk + (size_t)((dir*8 + w)*6) * 8 * 64;
        #pragma unroll
        for (int kt = 0; kt < 6; kt++)
            #pragma unroll
            for (int rt = 0; rt < 8; rt++) {
                uint4 t = wb[(kt*8 + rt)*64 + lane];
                u32x4_t f; f.x = t.x; f.y = t.y; f.z = t.z; f.w = t.w;
                if (kt < 4) asm("" : "+a"(f));          // pin to AGPR quad
                else        asm("" : "+v"(f));          // pin to arch VGPR quad
                aR[kt][rt] = f;
            }
    }
    // ---- LDS-tier A-frags (kt 6,7) ----
    {
        const uint4* wlb = wlt + (size_t)dir * 8192;
        for (int i = tid; i < 8192; i += 512) wt[i] = wlb[i];
    }
    if (tid < 256) hbuf[tid] = 0u;                      // zero both h buffers
    __syncthreads();

    const float* gib = gi + (size_t)dir * 4194304;
    float* hsb = hs + (size_t)dir * 1048576;
    const bool fw = (dir == 0);
    float cst = 0.f, hprev = 0.f;
    int sqprev = 0;
    const int c = tid;                                  // epilogue cell (tid<256)

    #pragma clang loop unroll(disable)
    for (int s = 0; s < S_LEN; s++) {
        const int sq = fw ? s : (S_LEN - 1 - s);

        // gi for this step's epilogue (issued early, consumed after B1)
        float gv0, gv1, gv2, gv3;
        if (tid < 256) {
            const float* gp = gib + (size_t)sq * 1024 + c;
            gv0 = gp[0]; gv1 = gp[256]; gv2 = gp[512]; gv3 = gp[768];
            // delayed hs store from previous step (drains under MFMA phase)
            if (s > 0) hsb[(size_t)sqprev * 256 + c] = hprev;
        }

        const char* hb = (const char*)hbuf + (s & 1) * 512;
        f32x4_t d[8];

        // kt = 0 (C = 0)
        {
            u32x4_t bq = *(const u32x4_t*)(hb + lg * 16);
            f16x8_t bk = __builtin_bit_cast(f16x8_t, bq);
            #pragma unroll
            for (int rt = 0; rt < 8; rt++)
                d[rt] = __builtin_amdgcn_mfma_f32_16x16x32_f16(
                            __builtin_bit_cast(f16x8_t, aR[0][rt]), bk,
                            (f32x4_t){0.f, 0.f, 0.f, 0.f}, 0, 0, 0);
        }
        // kt = 1..5 (register tier)
        #pragma unroll
        for (int kt = 1; kt < 6; kt++) {
            u32x4_t bq = *(const u32x4_t*)(hb + (kt*16 + lg*4) * 4);
            f16x8_t bk = __builtin_bit_cast(f16x8_t, bq);
            #pragma unroll
            for (int rt = 0; rt < 8; rt++)
                d[rt] = __builtin_amdgcn_mfma_f32_16x16x32_f16(
                            __builtin_bit_cast(f16x8_t, aR[kt][rt]), bk, d[rt], 0, 0, 0);
        }
        // kt = 6,7 (LDS tier, streamed)
        #pragma unroll
        for (int kt2 = 0; kt2 < 2; kt2++) {
            u32x4_t bq = *(const u32x4_t*)(hb + ((6 + kt2)*16 + lg*4) * 4);
            f16x8_t bk = __builtin_bit_cast(f16x8_t, bq);
            const uint4* wrow = wt + ((w*2 + kt2)*8) * 64 + lane;
            #pragma unroll
            for (int rt = 0; rt < 8; rt++) {
                u32x4_t ak = *(const u32x4_t*)&wrow[rt * 64];
                d[rt] = __builtin_amdgcn_mfma_f32_16x16x32_f16(
                            __builtin_bit_cast(f16x8_t, ak), bk, d[rt], 0, 0, 0);
            }
        }
        // D -> gates[] : lane lr==0 of each 16-group holds rows lg*4 + 0..3
        if (lr == 0) {
            #pragma unroll
            for (int rt = 0; rt < 8; rt++)
                *(f32x4_t*)&gates[w*128 + rt*16 + lg*4] = d[rt];
        }
        __syncthreads();                                 // B1: gates ready

        if (tid < 256) {
            float vi = gates[c]       + gv0;
            float vf = gates[256 + c] + gv1;
            float vg = gates[512 + c] + gv2;
            float vo = gates[768 + c] + gv3;
            float ig = sigm(vi), fg = sigm(vf), gt = ftanh(vg), og = sigm(vo);
            cst = fg * cst + ig * gt;
            float h = og * ftanh(cst);
            hprev = h; sqprev = sq;
            union { _Float16 hh; unsigned short u; } cv; cv.hh = (_Float16)h;
            ((unsigned short*)(hbuf + ((s + 1) & 1) * 128))[c] = cv.u;
        }
        __syncthreads();                                 // B2: next h buffer ready
    }
    if (tid < 256) hsb[(size_t)sqprev * 256 + c] = hprev; // final delayed store
}

// ---------------------------------------------------------------------------
// K6: feats[s][j] = b_tag[j] + hs_f[s]·W_tag[j][0:256] + hs_b[s]·W_tag[j][256:512]
// ---------------------------------------------------------------------------
__global__ void k_feats(const float* __restrict__ hs, const float* __restrict__ wtag,
                        const float* __restrict__ btag, float* __restrict__ feats) {
    int s = blockIdx.x, j = threadIdx.x;                 // 64 threads, 12 active
    if (j < 12) {
        const float* hf = hs + (size_t)s * 256;
        const float* hb = hs + 1048576 + (size_t)s * 256;
        const float* w = wtag + j * 512;
        float a0 = 0.f, a1 = 0.f, a2 = 0.f, a3 = 0.f;
        for (int k = 0; k < 256; k += 4) {
            a0 += hf[k] * w[k];     a1 += hf[k+1] * w[k+1];
            a2 += hf[k+2] * w[k+2]; a3 += hf[k+3] * w[k+3];
        }
        for (int k = 0; k < 256; k += 4) {
            a0 += hb[k] * w[256+k];     a1 += hb[k+1] * w[256+k+1];
            a2 += hb[k+2] * w[256+k+2]; a3 += hb[k+3] * w[256+k+3];
        }
        feats[s * 12 + j] = btag[j] + ((a0 + a1) + (a2 + a3));
    }
}

// ---------------------------------------------------------------------------
// K7: gold score (single block)
// ---------------------------------------------------------------------------
__global__ void k_gold(const float* __restrict__ feats, const int* __restrict__ tags,
                       const float* __restrict__ trans, float* __restrict__ scal) {
    __shared__ float red[256];
    int tid = threadIdx.x;
    float p = 0.f;
    for (int s = tid; s < S_LEN; s += 256) {
        int tg = tags[s];
        p += feats[s * 12 + tg];
        int prev = (s == 0) ? 10 : tags[s - 1];
        p += trans[prev * 12 + tg];
    }
    if (tid == 0) p += trans[tags[S_LEN - 1] * 12 + 11];
    red[tid] = p;
    __syncthreads();
    for (int off = 128; off; off >>= 1) {
        if (tid < off) red[tid] += red[tid + off];
        __syncthreads();
    }
    if (tid == 0) scal[0] = red[0];
}

// ---------------------------------------------------------------------------
// CRF as ordered log-matmul tree-reduction.  M_s[i][j] = trans[i][j] + feat[s][j].
// ---------------------------------------------------------------------------
__device__ __forceinline__ void lse_merge(const float* A, const float* B, float* C, int tid) {
    if (tid < 144) {
        int i = tid / 12, j = tid % 12;
        float m = -1e30f;
        #pragma unroll
        for (int k = 0; k < 12; k++) m = fmaxf(m, A[i * 12 + k] + B[k * 12 + j]);
        float sum = 0.f;
        #pragma unroll
        for (int k = 0; k < 12; k++) sum += __expf(A[i * 12 + k] + B[k * 12 + j] - m);
        C[tid] = m + __logf(sum);
    }
}

// K8: chunk products of 16 consecutive M_s (256 blocks)
__global__ void k_crf1(const float* __restrict__ feats, const float* __restrict__ trans,
                       float* __restrict__ chunks) {
    int b = blockIdx.x, tid = threadIdx.x;               // 192 threads, 144 active
    __shared__ float A[144], Bv[144], Tr[144];
    if (tid < 144) Tr[tid] = trans[tid];
    int s0 = b * 16;
    if (tid < 144) A[tid] = trans[tid] + feats[s0 * 12 + (tid % 12)];
    __syncthreads();
    float* cur = A; float* nxt = Bv;
    for (int s = s0 + 1; s < s0 + 16; s++) {
        if (tid < 144) {
            int i = tid / 12, j = tid % 12;
            float m = -1e30f;
            #pragma unroll
            for (int k = 0; k < 12; k++) m = fmaxf(m, cur[i * 12 + k] + Tr[k * 12 + j]);
            float sum = 0.f;
            #pragma unroll
            for (int k = 0; k < 12; k++) sum += __expf(cur[i * 12 + k] + Tr[k * 12 + j] - m);
            nxt[tid] = feats[s * 12 + j] + m + __logf(sum);
        }
        __syncthreads();
        float* tmp = cur; cur = nxt; nxt = tmp;
    }
    if (tid < 144) chunks[b * 144 + tid] = cur[tid];
}

// K9: fold 16 chunks each (16 blocks)
__global__ void k_crf2(const float* __restrict__ chunks, float* __restrict__ lvl2) {
    int b = blockIdx.x, tid = threadIdx.x;               // 192 threads
    __shared__ float A[144], Bv[144], Cc[144];
    if (tid < 144) A[tid] = chunks[(size_t)(b * 16) * 144 + tid];
    __syncthreads();
    for (int m2 = 1; m2 < 16; m2++) {
        if (tid < 144) Bv[tid] = chunks[(size_t)(b * 16 + m2) * 144 + tid];
        __syncthreads();
        lse_merge(A, Bv, Cc, tid);
        __syncthreads();
        if (tid < 144) A[tid] = Cc[tid];
        __syncthreads();
    }
    if (tid < 144) lvl2[b * 144 + tid] = A[tid];
}

// K10: final fold + score (1 block)
__global__ void k_crf3(const float* __restrict__ lvl2, const float* __restrict__ trans,
                       const float* __restrict__ scal, float* __restrict__ out) {
    __shared__ float A[144], Bv[144], Cc[144], alpha[12];
    int tid = threadIdx.x;                               // 192 threads
    if (tid < 144) A[tid] = lvl2[tid];
    __syncthreads();
    for (int m2 = 1; m2 < 16; m2++) {
        if (tid < 144) Bv[tid] = lvl2[m2 * 144 + tid];
        __syncthreads();
        lse_merge(A, Bv, Cc, tid);
        __syncthreads();
        if (tid < 144) A[tid] = Cc[tid];
        __syncthreads();
    }
    if (tid < 12) {
        int j = tid;
        float m = -1e30f;
        #pragma unroll
        for (int i = 0; i < 12; i++) {
            float v = ((i == 10) ? 0.f : -10000.f) + A[i * 12 + j];
            m = fmaxf(m, v);
        }
        float sum = 0.f;
        #pragma unroll
        for (int i = 0; i < 12; i++) {
            float v = ((i == 10) ? 0.f : -10000.f) + A[i * 12 + j];
            sum += __expf(v - m);
        }
        alpha[j] = m + __logf(sum) + trans[j * 12 + 11];
    }
    __syncthreads();
    if (tid == 0) {
        float m = -1e30f;
        #pragma unroll
        for (int j = 0; j < 12; j++) m = fmaxf(m, alpha[j]);
        float sum = 0.f;
        #pragma unroll
        for (int j = 0; j < 12; j++) sum += __expf(alpha[j] - m);
        out[0] = (m + __logf(sum)) - scal[0];
    }
}

// ---------------------------------------------------------------------------
extern "C" void kernel_launch(void* const* d_in, const int* in_sizes, int n_in,
                              void* d_out, int out_size, void* d_ws, size_t ws_size,
                              hipStream_t stream) {
    const int*   sentence = (const int*)d_in[0];
    const int*   chars    = (const int*)d_in[1];
    const int*   tags     = (const int*)d_in[2];
    const float* wemb     = (const float*)d_in[4];
    const float* cemb     = (const float*)d_in[5];
    const float* convw    = (const float*)d_in[6];
    const float* convb    = (const float*)d_in[7];
    const float* wihf     = (const float*)d_in[8];
    const float* whhf     = (const float*)d_in[9];
    const float* bf       = (const float*)d_in[10];
    const float* wihb     = (const float*)d_in[11];
    const float* whhb     = (const float*)d_in[12];
    const float* bb       = (const float*)d_in[13];
    const float* wtag     = (const float*)d_in[14];
    const float* btag     = (const float*)d_in[15];
    const float* trans    = (const float*)d_in[16];

    char* ws = (char*)d_ws;
    float* embeds = (float*)(ws + WS_EMBEDS);
    float* gi     = (float*)(ws + WS_GI);
    uint4* wpk    = (uint4*)(ws + WS_WPK);
    uint4* wlt    = (uint4*)(ws + WS_WLT);
    float* cfeat  = (float*)(ws + WS_CFEAT);
    float* hsbuf  = (float*)(ws + WS_HS);
    float* feats  = (float*)(ws + WS_FEATS);
    float* chunks = (float*)(ws + WS_CHUNKS);
    float* lvl2   = (float*)(ws + WS_LVL2);
    float* scal   = (float*)(ws + WS_SCAL);

    hipFuncSetAttribute((const void*)k_lstm,
                        hipFuncAttributeMaxDynamicSharedMemorySize, LSTM_LDS_BYTES);

    k_pack<<<256, 256, 0, stream>>>(whhf, whhb, wpk, wlt);
    k_charcnn<<<4096, 128, 0, stream>>>(chars, cemb, convw, convb, cfeat);
    k_embeds<<<4096, 128, 0, stream>>>(sentence, wemb, cfeat, embeds);
    k_gemm<<<dim3(64, 32), 256, 0, stream>>>(embeds, wihf, wihb, bf, bb, gi);
    k_lstm<<<2, 512, LSTM_LDS_BYTES, stream>>>(wpk, wlt, gi, hsbuf);
    k_feats<<<4096, 64, 0, stream>>>(hsbuf, wtag, btag, feats);
    k_gold<<<1, 256, 0, stream>>>(feats, tags, trans, scal);
    k_crf1<<<256, 192, 0, stream>>>(feats, trans, chunks);
    k_crf2<<<16, 192, 0, stream>>>(chunks, lvl2);
    k_crf3<<<1, 192, 0, stream>>>(lvl2, trans, scal, (float*)d_out);
}